// Round 5
// baseline (158.010 us; speedup 1.0000x reference)
//
#include <hip/hip_runtime.h>
#include <hip/hip_bf16.h>

#define BATCH 2
#define DEPTH 64
#define HH 128
#define WW 128
#define SLICES (BATCH*DEPTH)
#define SLICE_ELEMS (HH*WW)
#define NELEM (SLICES*SLICE_ELEMS)
#define NV4 (NELEM/4)
#define RBLK 1024

// ---------------- K1: fused column EDT + row min-plus, one block per slice -------------
// combined(p) = distance to nearest opposite-class pixel (== dst+inv: same-class term
// is exactly 0). Mask build uses all 8 waves; forward/backward column scans run
// CONCURRENTLY on different waves (two LDS buffers); merge+square pass; then the
// early-exit row min-plus. Also zeros the global accumulators (block 0).
__global__ __launch_bounds__(512) void edt_kernel(const float* __restrict__ y_pred,
        float* __restrict__ combined, float* __restrict__ maxdst,
        double* __restrict__ acc, int* __restrict__ counter)
{
    __shared__ unsigned mm_sh[WW][4];     // 2 KB: column bitmasks
    __shared__ unsigned tmpF[HH][WW];     // 64 KB: forward raw (di<<16|dd), later packed sq
    __shared__ unsigned tmpB[HH][WW];     // 64 KB: backward raw
    __shared__ float wred[8];
    int s = blockIdx.x;
    int t = threadIdx.x;
    if (s == 0 && t < 6) {                // zero loss accumulators + done-counter
        if (t < 5) acc[t] = 0.0; else counter[0] = 0;
    }
    const float* base = y_pred + (size_t)s * SLICE_ELEMS;

    // mask build: thread -> (col = t&127, group g = t>>7), rows g*32..g*32+31
    {
        int col = t & (WW-1);
        int g = t >> 7;
        unsigned accm = 0u;
        #pragma unroll
        for (int ii = 0; ii < 32; ++ii) {
            int r = g*32 + ii;
            accm |= (base[r*WW + col] > 0.7f ? 1u : 0u) << ii;
        }
        mm_sh[col][g] = accm;
    }
    __syncthreads();

    if (t < WW) {
        // forward scan of column t (rows 0 -> 127), raw distances
        int dd = 300, di = 300;
        #pragma unroll
        for (int g = 0; g < 4; ++g) {
            unsigned mg = mm_sh[t][g];
            #pragma unroll
            for (int ii = 0; ii < 32; ++ii) {
                int i = g*32 + ii;
                int fg = (mg >> ii) & 1;
                dd = fg ? dd + 1 : 0;      // dist to nearest bg above
                di = fg ? 0 : di + 1;      // dist to nearest fg above
                tmpF[i][t] = ((unsigned)di << 16) | (unsigned)dd;
            }
        }
    } else if (t < 2*WW) {
        // backward scan of column t-128 (rows 127 -> 0), concurrent with forward
        int c = t - WW;
        int dd = 300, di = 300;
        #pragma unroll
        for (int g = 3; g >= 0; --g) {
            unsigned mg = mm_sh[c][g];
            #pragma unroll
            for (int ii = 31; ii >= 0; --ii) {
                int i = g*32 + ii;
                int fg = (mg >> ii) & 1;
                dd = fg ? dd + 1 : 0;
                di = fg ? 0 : di + 1;
                tmpB[i][c] = ((unsigned)di << 16) | (unsigned)dd;
            }
        }
    }
    __syncthreads();

    // merge + square + sentinel: 16384 cells / 512 threads, stride-512 (bank-free)
    {
        unsigned* F = &tmpF[0][0];
        unsigned* B = &tmpB[0][0];
        #pragma unroll
        for (int k = 0; k < 32; ++k) {
            int c = k*512 + t;
            unsigned pf = F[c], pb = B[c];
            int fd = min((int)(pf & 0xFFFFu), (int)(pb & 0xFFFFu));
            int fi = min((int)(pf >> 16),     (int)(pb >> 16));
            unsigned sd = (fd >= 128) ? 0xFFFFu : (unsigned)(fd*fd);
            unsigned si = (fi >= 128) ? 0xFFFFu : (unsigned)(fi*fi);
            F[c] = (si << 16) | sd;
        }
    }
    __syncthreads();

    // row phase: 4 rows per iteration (512 threads = 4 rows x 128 cols)
    int j  = t & (WW-1);
    int ri = t >> 7;
    float dmax = 0.0f;
    float* cbase = combined + (size_t)s * SLICE_ELEMS;
    for (int it = 0; it < 32; ++it) {
        int i = it*4 + ri;
        unsigned p = tmpF[i][j];
        unsigned rawd = p & 0xFFFFu, rawi = p >> 16;
        int cfg = (rawi == 0u);            // foreground iff dist^2-to-1 == 0
        unsigned rsel = cfg ? rawd : rawi; // opposite-class column dist^2
        float bd = (rsel == 0xFFFFu) ? 1e20f : (float)rsel;
        for (int r = 1; r < WW; ++r) {
            float r2 = (float)(r*r);
            if (__all(r2 >= bd)) break;    // exact: candidates only grow past here
            int jl = j - r, jr = j + r;
            unsigned pl = tmpF[i][jl & (WW-1)];
            unsigned pr = tmpF[i][jr & (WW-1)];
            unsigned sl = cfg ? (pl & 0xFFFFu) : (pl >> 16);
            unsigned sr = cfg ? (pr & 0xFFFFu) : (pr >> 16);
            float gl = (sl == 0xFFFFu) ? 1e20f : (float)sl;
            float gr = (sr == 0xFFFFu) ? 1e20f : (float)sr;
            gl = (jl >= 0) ? gl : 3e38f;
            gr = (jr < WW) ? gr : 3e38f;
            bd = fminf(bd, r2 + fminf(gl, gr));
        }
        float dco = sqrtf(bd);
        cbase[i*WW + j] = dco;
        if (cfg) dmax = fmaxf(dmax, dco);  // dst component lives only on fg pixels
    }
    for (int off = 32; off > 0; off >>= 1)
        dmax = fmaxf(dmax, __shfl_down(dmax, off));
    if ((t & 63) == 0) wred[t >> 6] = dmax;
    __syncthreads();
    if (t == 0) {
        float mx = 0.0f;
        #pragma unroll
        for (int w = 0; w < 8; ++w) mx = fmaxf(mx, wred[w]);
        maxdst[s] = mx;                    // present(s) <=> mx > 0; thresh = mx at last
    }
}

// ---------------- K2: range (ballot) + vectorized reduce + last-block final ------------
__global__ __launch_bounds__(256) void reduce_kernel(const float4* __restrict__ yp4,
        const float4* __restrict__ yt4, const float4* __restrict__ cb4,
        const float* __restrict__ maxdst,
        double* __restrict__ acc, int* __restrict__ counter, float* __restrict__ out)
{
    __shared__ int sh_f[2], sh_l[2];
    __shared__ float sh_t[2];
    int t = threadIdx.x;
    if (t < 128) {                         // wave0 -> batch0, wave1 -> batch1
        int b = t >> 6, d = t & 63;
        float mx = maxdst[b*DEPTH + d];
        unsigned long long mask = __ballot(mx > 0.0f);
        int f = 0, l = DEPTH-1;
        if (mask) {
            f = __ffsll(mask) - 1;
            l = 63 - __clzll(mask);
        }
        if (d == 0) { sh_f[b] = f; sh_l[b] = l; }
        if (d == l) sh_t[b] = mx;          // thresh[b] (0 if nothing present)
    }
    __syncthreads();
    int f0 = sh_f[0], l0 = sh_l[0], f1 = sh_f[1], l1 = sh_l[1];
    float th0 = sh_t[0], th1 = sh_t[1];

    float v0=0.f, v1=0.f, v2=0.f, v3=0.f, v4=0.f;
    for (int i4 = blockIdx.x*256 + t; i4 < NV4; i4 += RBLK*256) {
        int idx = i4 << 2;
        int b = idx >> 20;                 // D*H*W = 2^20
        int d = (idx >> 14) & (DEPTH-1);   // H*W = 2^14
        float4 p = yp4[i4];
        float4 q = yt4[i4];
        float4 cc = cb4[i4];
        bool inr = b ? (d >= f1 && d <= l1) : (d >= f0 && d <= l0);
        float th = b ? th1 : th0;
        float c0 = fminf(inr ? cc.x : 0.0f, th);
        float c1 = fminf(inr ? cc.y : 0.0f, th);
        float c2 = fminf(inr ? cc.z : 0.0f, th);
        float c3 = fminf(inr ? cc.w : 0.0f, th);
        float m0 = (q.x > 0.f) ? 1.f : 0.f;
        float m1 = (q.y > 0.f) ? 1.f : 0.f;
        float m2 = (q.z > 0.f) ? 1.f : 0.f;
        float m3 = (q.w > 0.f) ? 1.f : 0.f;
        v0 += p.x*q.x + p.y*q.y + p.z*q.z + p.w*q.w;
        v1 += p.x + p.y + p.z + p.w;
        v2 += q.x + q.y + q.z + q.w;
        v3 += m0*c0 + m1*c1 + m2*c2 + m3*c3;
        v4 += m0 + m1 + m2 + m3;
    }
    for (int off = 32; off > 0; off >>= 1) {
        v0 += __shfl_down(v0, off);
        v1 += __shfl_down(v1, off);
        v2 += __shfl_down(v2, off);
        v3 += __shfl_down(v3, off);
        v4 += __shfl_down(v4, off);
    }
    __shared__ float wsum[4][5];
    int wv = t >> 6;
    if ((t & 63) == 0) {
        wsum[wv][0]=v0; wsum[wv][1]=v1; wsum[wv][2]=v2; wsum[wv][3]=v3; wsum[wv][4]=v4;
    }
    __syncthreads();
    if (t == 0) {
        atomicAdd(&acc[0], (double)(wsum[0][0]+wsum[1][0]+wsum[2][0]+wsum[3][0]));
        atomicAdd(&acc[1], (double)(wsum[0][1]+wsum[1][1]+wsum[2][1]+wsum[3][1]));
        atomicAdd(&acc[2], (double)(wsum[0][2]+wsum[1][2]+wsum[2][2]+wsum[3][2]));
        atomicAdd(&acc[3], (double)(wsum[0][3]+wsum[1][3]+wsum[2][3]+wsum[3][3]));
        atomicAdd(&acc[4], (double)(wsum[0][4]+wsum[1][4]+wsum[2][4]+wsum[3][4]));
        __threadfence();
        int old = atomicAdd(counter, 1);
        if (old == RBLK - 1) {             // last block: finalize
            __threadfence();
            double inter = atomicAdd(&acc[0], 0.0);
            double spred = atomicAdd(&acc[1], 0.0);
            double strue = atomicAdd(&acc[2], 0.0);
            double sel   = atomicAdd(&acc[3], 0.0);
            double cnt   = atomicAdd(&acc[4], 0.0);
            double dice = 2.0 * inter / (spred + strue + 1e-6);
            double mean_sel = sel / cnt;
            out[0] = (float)((1.0 - dice) + 3.0 * fabs(1.0 - mean_sel));
        }
    }
}

extern "C" void kernel_launch(void* const* d_in, const int* in_sizes, int n_in,
                              void* d_out, int out_size, void* d_ws, size_t ws_size,
                              hipStream_t stream) {
    const float* y_pred = (const float*)d_in[0];
    const float* y_true = (const float*)d_in[1];
    float* out = (float*)d_out;
    char* ws = (char*)d_ws;

    float*  maxdst   = (float*)(ws + 128);     // SLICES floats
    double* acc      = (double*)(ws + 1024);   // 5 doubles (loss accumulators)
    int*    counter  = (int*)(ws + 1088);      // done-counter
    float*  combined = (float*)(ws + 32768);   // 8.4 MB, 16B-aligned

    edt_kernel<<<SLICES, 512, 0, stream>>>(y_pred, combined, maxdst, acc, counter);
    reduce_kernel<<<RBLK, 256, 0, stream>>>((const float4*)y_pred, (const float4*)y_true,
                                            (const float4*)combined, maxdst, acc, counter, out);
}

// Round 6
// 96.284 us; speedup vs baseline: 1.6411x; 1.6411x over previous
//
#include <hip/hip_runtime.h>
#include <hip/hip_bf16.h>

#define BATCH 2
#define DEPTH 64
#define HH 128
#define WW 128
#define SLICES (BATCH*DEPTH)
#define SLICE_ELEMS (HH*WW)
#define NELEM (SLICES*SLICE_ELEMS)
#define NV4 (NELEM/4)
#define RBLK 1024

// ---------------- K1: fused column EDT + row min-plus, one block per slice -------------
// combined(p) = distance to nearest opposite-class pixel (== dst+inv: same-class term
// is exactly 0). Mask build uses all 8 waves; forward/backward column scans run
// CONCURRENTLY on different waves (two LDS buffers); merge+square pass; then the
// early-exit row min-plus.
__global__ __launch_bounds__(512) void edt_kernel(const float* __restrict__ y_pred,
        float* __restrict__ combined, float* __restrict__ maxdst)
{
    __shared__ unsigned mm_sh[WW][4];     // 2 KB: column bitmasks
    __shared__ unsigned tmpF[HH][WW];     // 64 KB: forward raw (di<<16|dd), later packed sq
    __shared__ unsigned tmpB[HH][WW];     // 64 KB: backward raw
    __shared__ float wred[8];
    int s = blockIdx.x;
    int t = threadIdx.x;
    const float* base = y_pred + (size_t)s * SLICE_ELEMS;

    // mask build: thread -> (col = t&127, group g = t>>7), rows g*32..g*32+31
    {
        int col = t & (WW-1);
        int g = t >> 7;
        unsigned accm = 0u;
        #pragma unroll
        for (int ii = 0; ii < 32; ++ii) {
            int r = g*32 + ii;
            accm |= (base[r*WW + col] > 0.7f ? 1u : 0u) << ii;
        }
        mm_sh[col][g] = accm;
    }
    __syncthreads();

    if (t < WW) {
        // forward scan of column t (rows 0 -> 127), raw distances
        int dd = 300, di = 300;
        #pragma unroll
        for (int g = 0; g < 4; ++g) {
            unsigned mg = mm_sh[t][g];
            #pragma unroll
            for (int ii = 0; ii < 32; ++ii) {
                int i = g*32 + ii;
                int fg = (mg >> ii) & 1;
                dd = fg ? dd + 1 : 0;      // dist to nearest bg above
                di = fg ? 0 : di + 1;      // dist to nearest fg above
                tmpF[i][t] = ((unsigned)di << 16) | (unsigned)dd;
            }
        }
    } else if (t < 2*WW) {
        // backward scan of column t-128 (rows 127 -> 0), concurrent with forward
        int c = t - WW;
        int dd = 300, di = 300;
        #pragma unroll
        for (int g = 3; g >= 0; --g) {
            unsigned mg = mm_sh[c][g];
            #pragma unroll
            for (int ii = 31; ii >= 0; --ii) {
                int i = g*32 + ii;
                int fg = (mg >> ii) & 1;
                dd = fg ? dd + 1 : 0;
                di = fg ? 0 : di + 1;
                tmpB[i][c] = ((unsigned)di << 16) | (unsigned)dd;
            }
        }
    }
    __syncthreads();

    // merge + square + sentinel: 16384 cells / 512 threads, stride-512 (bank-free)
    {
        unsigned* F = &tmpF[0][0];
        unsigned* B = &tmpB[0][0];
        #pragma unroll
        for (int k = 0; k < 32; ++k) {
            int c = k*512 + t;
            unsigned pf = F[c], pb = B[c];
            int fd = min((int)(pf & 0xFFFFu), (int)(pb & 0xFFFFu));
            int fi = min((int)(pf >> 16),     (int)(pb >> 16));
            unsigned sd = (fd >= 128) ? 0xFFFFu : (unsigned)(fd*fd);
            unsigned si = (fi >= 128) ? 0xFFFFu : (unsigned)(fi*fi);
            F[c] = (si << 16) | sd;
        }
    }
    __syncthreads();

    // row phase: 4 rows per iteration (512 threads = 4 rows x 128 cols)
    int j  = t & (WW-1);
    int ri = t >> 7;
    float dmax = 0.0f;
    float* cbase = combined + (size_t)s * SLICE_ELEMS;
    for (int it = 0; it < 32; ++it) {
        int i = it*4 + ri;
        unsigned p = tmpF[i][j];
        unsigned rawd = p & 0xFFFFu, rawi = p >> 16;
        int cfg = (rawi == 0u);            // foreground iff dist^2-to-1 == 0
        unsigned rsel = cfg ? rawd : rawi; // opposite-class column dist^2
        float bd = (rsel == 0xFFFFu) ? 1e20f : (float)rsel;
        for (int r = 1; r < WW; ++r) {
            float r2 = (float)(r*r);
            if (__all(r2 >= bd)) break;    // exact: candidates only grow past here
            int jl = j - r, jr = j + r;
            unsigned pl = tmpF[i][jl & (WW-1)];
            unsigned pr = tmpF[i][jr & (WW-1)];
            unsigned sl = cfg ? (pl & 0xFFFFu) : (pl >> 16);
            unsigned sr = cfg ? (pr & 0xFFFFu) : (pr >> 16);
            float gl = (sl == 0xFFFFu) ? 1e20f : (float)sl;
            float gr = (sr == 0xFFFFu) ? 1e20f : (float)sr;
            gl = (jl >= 0) ? gl : 3e38f;
            gr = (jr < WW) ? gr : 3e38f;
            bd = fminf(bd, r2 + fminf(gl, gr));
        }
        float dco = sqrtf(bd);
        cbase[i*WW + j] = dco;
        if (cfg) dmax = fmaxf(dmax, dco);  // dst component lives only on fg pixels
    }
    for (int off = 32; off > 0; off >>= 1)
        dmax = fmaxf(dmax, __shfl_down(dmax, off));
    if ((t & 63) == 0) wred[t >> 6] = dmax;
    __syncthreads();
    if (t == 0) {
        float mx = 0.0f;
        #pragma unroll
        for (int w = 0; w < 8; ++w) mx = fmaxf(mx, wred[w]);
        maxdst[s] = mx;                    // present(s) <=> mx > 0; thresh = mx at last
    }
}

// ---------------- K2: range (ballot) + vectorized reduce -> per-block partials ---------
__global__ __launch_bounds__(256) void reduce_kernel(const float4* __restrict__ yp4,
        const float4* __restrict__ yt4, const float4* __restrict__ cb4,
        const float* __restrict__ maxdst, float* __restrict__ partials)
{
    __shared__ int sh_f[2], sh_l[2];
    __shared__ float sh_t[2];
    int t = threadIdx.x;
    if (t < 128) {                         // wave0 -> batch0, wave1 -> batch1
        int b = t >> 6, d = t & 63;
        float mx = maxdst[b*DEPTH + d];
        unsigned long long mask = __ballot(mx > 0.0f);
        int f = 0, l = DEPTH-1;
        if (mask) {
            f = __ffsll(mask) - 1;
            l = 63 - __clzll(mask);
        }
        if (d == 0) { sh_f[b] = f; sh_l[b] = l; }
        if (d == l) sh_t[b] = mx;          // thresh[b] (0 if nothing present)
    }
    __syncthreads();
    int f0 = sh_f[0], l0 = sh_l[0], f1 = sh_f[1], l1 = sh_l[1];
    float th0 = sh_t[0], th1 = sh_t[1];

    float v0=0.f, v1=0.f, v2=0.f, v3=0.f, v4=0.f;
    #pragma unroll
    for (int k = 0; k < 2; ++k) {          // NV4 == RBLK*256*2 exactly
        int i4 = k*RBLK*256 + blockIdx.x*256 + t;
        int idx = i4 << 2;
        int b = idx >> 20;                 // D*H*W = 2^20
        int d = (idx >> 14) & (DEPTH-1);   // H*W = 2^14
        float4 p = yp4[i4];
        float4 q = yt4[i4];
        float4 cc = cb4[i4];
        bool inr = b ? (d >= f1 && d <= l1) : (d >= f0 && d <= l0);
        float th = b ? th1 : th0;
        float c0 = fminf(inr ? cc.x : 0.0f, th);
        float c1 = fminf(inr ? cc.y : 0.0f, th);
        float c2 = fminf(inr ? cc.z : 0.0f, th);
        float c3 = fminf(inr ? cc.w : 0.0f, th);
        float m0 = (q.x > 0.f) ? 1.f : 0.f;
        float m1 = (q.y > 0.f) ? 1.f : 0.f;
        float m2 = (q.z > 0.f) ? 1.f : 0.f;
        float m3 = (q.w > 0.f) ? 1.f : 0.f;
        v0 += p.x*q.x + p.y*q.y + p.z*q.z + p.w*q.w;
        v1 += p.x + p.y + p.z + p.w;
        v2 += q.x + q.y + q.z + q.w;
        v3 += m0*c0 + m1*c1 + m2*c2 + m3*c3;
        v4 += m0 + m1 + m2 + m3;
    }
    for (int off = 32; off > 0; off >>= 1) {
        v0 += __shfl_down(v0, off);
        v1 += __shfl_down(v1, off);
        v2 += __shfl_down(v2, off);
        v3 += __shfl_down(v3, off);
        v4 += __shfl_down(v4, off);
    }
    __shared__ float wsum[4][5];
    int wv = t >> 6;
    if ((t & 63) == 0) {
        wsum[wv][0]=v0; wsum[wv][1]=v1; wsum[wv][2]=v2; wsum[wv][3]=v3; wsum[wv][4]=v4;
    }
    __syncthreads();
    if (t == 0) {
        #pragma unroll
        for (int qd = 0; qd < 5; ++qd)
            partials[qd*RBLK + blockIdx.x] = wsum[0][qd]+wsum[1][qd]+wsum[2][qd]+wsum[3][qd];
    }
}

// ---------------- K3: final scalar ----------------
__global__ __launch_bounds__(1024) void final_kernel(const float* __restrict__ partials,
                                                     float* __restrict__ out)
{
    int t = threadIdx.x;
    double l0 = (double)partials[0*RBLK + t];
    double l1 = (double)partials[1*RBLK + t];
    double l2 = (double)partials[2*RBLK + t];
    double l3 = (double)partials[3*RBLK + t];
    double l4 = (double)partials[4*RBLK + t];
    for (int off = 32; off > 0; off >>= 1) {
        l0 += __shfl_down(l0, off);
        l1 += __shfl_down(l1, off);
        l2 += __shfl_down(l2, off);
        l3 += __shfl_down(l3, off);
        l4 += __shfl_down(l4, off);
    }
    __shared__ double ds[16][5];
    int wv = t >> 6;
    if ((t & 63) == 0) { ds[wv][0]=l0; ds[wv][1]=l1; ds[wv][2]=l2; ds[wv][3]=l3; ds[wv][4]=l4; }
    __syncthreads();
    if (t == 0) {
        double inter=0, spred=0, strue=0, sel=0, cnt=0;
        for (int w = 0; w < 16; ++w) {
            inter += ds[w][0]; spred += ds[w][1]; strue += ds[w][2];
            sel   += ds[w][3]; cnt   += ds[w][4];
        }
        double dice = 2.0 * inter / (spred + strue + 1e-6);
        double mean_sel = sel / cnt;
        double loss = (1.0 - dice) + 3.0 * fabs(1.0 - mean_sel);
        out[0] = (float)loss;
    }
}

extern "C" void kernel_launch(void* const* d_in, const int* in_sizes, int n_in,
                              void* d_out, int out_size, void* d_ws, size_t ws_size,
                              hipStream_t stream) {
    const float* y_pred = (const float*)d_in[0];
    const float* y_true = (const float*)d_in[1];
    float* out = (float*)d_out;
    char* ws = (char*)d_ws;

    float* maxdst   = (float*)(ws + 128);      // SLICES floats
    float* partials = (float*)(ws + 2048);     // 5*1024 floats = 20 KB
    float* combined = (float*)(ws + 32768);    // 8.4 MB, 16B-aligned

    edt_kernel<<<SLICES, 512, 0, stream>>>(y_pred, combined, maxdst);
    reduce_kernel<<<RBLK, 256, 0, stream>>>((const float4*)y_pred, (const float4*)y_true,
                                            (const float4*)combined, maxdst, partials);
    final_kernel<<<1, 1024, 0, stream>>>(partials, out);
}